// Round 1
// baseline (869.718 us; speedup 1.0000x reference)
//
#include <hip/hip_runtime.h>
#include <math.h>

// ---------------------------------------------------------------------------
// GATv2 x2 layers on MI355X. fp32 throughout.
// Pipeline:
//   memset deg/cursor -> k_count_deg -> k_scan (rowptr) -> k_scatter (CSR)
//   -> k_loop_attr -> k_gemm1 (xl1,xr1) -> k_logits1 -> k_node1 (h)
//   -> k_gemv2 (xl2,xr2) -> k_logits2 -> k_node2 (out)
// ---------------------------------------------------------------------------

__global__ void k_count_deg(const int* __restrict__ dst, int* __restrict__ deg, int E) {
    int i = blockIdx.x * blockDim.x + threadIdx.x;
    if (i < E) atomicAdd(&deg[dst[i]], 1);
}

// single-block exclusive scan of deg -> rowptr (N up to ~10^5; wave-shuffle based)
__global__ __launch_bounds__(1024) void k_scan(const int* __restrict__ deg,
                                               int* __restrict__ rowptr, int N) {
    __shared__ int wsum[16];
    __shared__ int s_run;
    int t = threadIdx.x;
    int l = t & 63;
    int w = t >> 6;
    if (t == 0) s_run = 0;
    __syncthreads();
    for (int base = 0; base < N; base += 1024) {
        int i = base + t;
        int v = (i < N) ? deg[i] : 0;
        int sc = v;  // inclusive wave scan
        #pragma unroll
        for (int off = 1; off < 64; off <<= 1) {
            int y = __shfl_up(sc, off);
            if (l >= off) sc += y;
        }
        if (l == 63) wsum[w] = sc;
        __syncthreads();
        if (w == 0) {
            int pv = (l < 16) ? wsum[l] : 0;
            int psc = pv;
            #pragma unroll
            for (int off = 1; off < 16; off <<= 1) {
                int y = __shfl_up(psc, off);
                if (l >= off) psc += y;
            }
            if (l < 16) wsum[l] = psc - pv;  // exclusive wave offsets
        }
        __syncthreads();
        if (i < N) rowptr[i] = s_run + wsum[w] + sc - v;
        __syncthreads();                      // everyone done reading s_run/wsum
        if (t == 1023) s_run += wsum[15] + sc;  // chunk total
        __syncthreads();
    }
    if (t == 0) rowptr[N] = s_run;
}

__global__ void k_scatter(const int* __restrict__ dst, const int* __restrict__ rowptr,
                          int* __restrict__ cursor, int* __restrict__ csr, int E) {
    int i = blockIdx.x * blockDim.x + threadIdx.x;
    if (i < E) {
        int d = dst[i];
        int pos = rowptr[d] + atomicAdd(&cursor[d], 1);
        csr[pos] = i;
    }
}

// loop_attr[n][k] = sum_{incoming e} edge_attr[e][k] / max(deg,1)
__global__ void k_loop_attr(const float* __restrict__ edge_attr, const int* __restrict__ rowptr,
                            const int* __restrict__ csr, float* __restrict__ loop_attr, int N) {
    int idx = blockIdx.x * blockDim.x + threadIdx.x;  // n*16 + k
    if (idx >= N * 16) return;
    int n = idx >> 4, k = idx & 15;
    int rs = rowptr[n], re = rowptr[n + 1];
    float s = 0.f;
    for (int j = rs; j < re; ++j) s += edge_attr[(size_t)csr[j] * 16 + k];
    int dg = re - rs;
    loop_attr[idx] = s / (float)(dg > 1 ? dg : 1);
}

// xl1 = x @ Wl1, xr1 = x @ Wr1  (N x 128 @ 128 x 128), 32 rows per block
__global__ __launch_bounds__(256) void k_gemm1(const float* __restrict__ x,
                                               const float* __restrict__ Wl,
                                               const float* __restrict__ Wr,
                                               float* __restrict__ xl, float* __restrict__ xr,
                                               int N) {
    __shared__ float xs[32 * 128];
    int r0 = blockIdx.x * 32;
    int t = threadIdx.x;
    for (int i = t * 4; i < 32 * 128; i += 256 * 4) {
        int r = i >> 7;
        float4 v = make_float4(0.f, 0.f, 0.f, 0.f);
        if (r0 + r < N) v = *(const float4*)(&x[(size_t)(r0 + r) * 128 + (i & 127)]);
        *(float4*)(&xs[i]) = v;
    }
    __syncthreads();
    int c = t & 127;
    int rbase = (t >> 7) * 16;  // 0 or 16
    float accl[16], accr[16];
    #pragma unroll
    for (int r = 0; r < 16; ++r) { accl[r] = 0.f; accr[r] = 0.f; }
    for (int k = 0; k < 128; ++k) {
        float wl = Wl[k * 128 + c];
        float wr = Wr[k * 128 + c];
        #pragma unroll
        for (int r = 0; r < 16; ++r) {
            float xv = xs[(rbase + r) * 128 + k];
            accl[r] += xv * wl;
            accr[r] += xv * wr;
        }
    }
    #pragma unroll
    for (int r = 0; r < 16; ++r) {
        int row = r0 + rbase + r;
        if (row < N) {
            xl[(size_t)row * 128 + c] = accl[r];
            xr[(size_t)row * 128 + c] = accr[r];
        }
    }
}

// layer-1 logits per augmented edge (wave per edge; lane l owns channels l, l+64)
__global__ __launch_bounds__(256) void k_logits1(
    const int* __restrict__ src, const int* __restrict__ dst,
    const float* __restrict__ edge_attr, const float* __restrict__ loop_attr,
    const float* __restrict__ xl, const float* __restrict__ xr,
    const float* __restrict__ We, const float* __restrict__ att,
    float* __restrict__ logits, int E, int N) {
    __shared__ float sWe[16 * 128];
    int t = threadIdx.x;
    for (int i = t; i < 16 * 128; i += 256) sWe[i] = We[i];
    __syncthreads();
    int l = t & 63;
    int m = (blockIdx.x * 256 + t) >> 6;  // global wave id == edge id
    int M = E + N;
    if (m >= M) return;
    int s, d;
    const float* ea;
    if (m < E) { s = src[m]; d = dst[m]; ea = edge_attr + (size_t)m * 16; }
    else       { s = d = m - E;          ea = loop_attr + (size_t)(m - E) * 16; }
    float eav = ea[l & 15];  // lanes 0..15 hold ea[0..15]
    float a0 = att[l], a1 = att[l + 64];
    float ep0 = 0.f, ep1 = 0.f;
    #pragma unroll
    for (int k = 0; k < 16; ++k) {
        float ak = __shfl(eav, k);
        ep0 += ak * sWe[k * 128 + l];
        ep1 += ak * sWe[k * 128 + 64 + l];
    }
    float v0 = xl[(size_t)s * 128 + l] + xr[(size_t)d * 128 + l] + ep0;
    float v1 = xl[(size_t)s * 128 + 64 + l] + xr[(size_t)d * 128 + 64 + l] + ep1;
    v0 = v0 > 0.f ? v0 : 0.2f * v0;
    v1 = v1 > 0.f ? v1 : 0.2f * v1;
    float p0 = a0 * v0, p1 = a1 * v1;
    #pragma unroll
    for (int ms = 1; ms < 32; ms <<= 1) {  // reduce within 32-lane halves
        p0 += __shfl_xor(p0, ms);
        p1 += __shfl_xor(p1, ms);
    }
    // lanes 0-31 hold heads {0,2}; lanes 32-63 heads {1,3}
    if (l == 0)  { logits[(size_t)m * 4 + 0] = p0; logits[(size_t)m * 4 + 2] = p1; }
    if (l == 32) { logits[(size_t)m * 4 + 1] = p0; logits[(size_t)m * 4 + 3] = p1; }
}

// layer-1 per-node softmax + aggregation + inter-layer leaky_relu -> h
__global__ __launch_bounds__(256) void k_node1(
    const int* __restrict__ src, const int* __restrict__ rowptr, const int* __restrict__ csr,
    const float* __restrict__ logits, const float* __restrict__ xl,
    float* __restrict__ hout, int E, int N) {
    int t = threadIdx.x;
    int l = t & 63;
    int n = (blockIdx.x * 256 + t) >> 6;  // wave per node
    if (n >= N) return;
    int rs = rowptr[n], re = rowptr[n + 1];
    int h4 = l & 3;   // head for the reduce phase
    int j0 = l >> 2;  // 0..15 edge-subset
    size_t selfbase = (size_t)(E + n) * 4;
    // pass 1: per-head max (self loop guarantees finite)
    float mx = logits[selfbase + h4];
    for (int j = rs + j0; j < re; j += 16)
        mx = fmaxf(mx, logits[(size_t)csr[j] * 4 + h4]);
    #pragma unroll
    for (int ms = 4; ms < 64; ms <<= 1) mx = fmaxf(mx, __shfl_xor(mx, ms));
    // pass 2: per-head denom
    float sm = (j0 == 0) ? expf(logits[selfbase + h4] - mx) : 0.f;
    for (int j = rs + j0; j < re; j += 16)
        sm += expf(logits[(size_t)csr[j] * 4 + h4] - mx);
    #pragma unroll
    for (int ms = 4; ms < 64; ms <<= 1) sm += __shfl_xor(sm, ms);
    float rd = 1.f / (sm + 1e-16f);
    // broadcast per-head (m, 1/denom): lane h (h<4) holds head h's values
    int h0 = l >> 5;      // channels l      -> heads 0/1
    int h1 = 2 + h0;      // channels l+64   -> heads 2/3
    float m0 = __shfl(mx, h0), m1 = __shfl(mx, h1);
    float r0 = __shfl(rd, h0), r1 = __shfl(rd, h1);
    float acc0 = 0.f, acc1 = 0.f;
    {   // self loop (source = n)
        float w0 = expf(logits[selfbase + h0] - m0) * r0;
        float w1 = expf(logits[selfbase + h1] - m1) * r1;
        acc0 += w0 * xl[(size_t)n * 128 + l];
        acc1 += w1 * xl[(size_t)n * 128 + 64 + l];
    }
    for (int j = rs; j < re; ++j) {
        int eid = csr[j];
        int sv = src[eid];
        float w0 = expf(logits[(size_t)eid * 4 + h0] - m0) * r0;
        float w1 = expf(logits[(size_t)eid * 4 + h1] - m1) * r1;
        acc0 += w0 * xl[(size_t)sv * 128 + l];
        acc1 += w1 * xl[(size_t)sv * 128 + 64 + l];
    }
    acc0 = acc0 > 0.f ? acc0 : 0.01f * acc0;  // inter-layer leaky_relu
    acc1 = acc1 > 0.f ? acc1 : 0.01f * acc1;
    hout[(size_t)n * 128 + l] = acc0;
    hout[(size_t)n * 128 + 64 + l] = acc1;
}

// xl2 = h @ Wl2 (128x4), xr2 = h @ Wr2 — wave per node
__global__ __launch_bounds__(256) void k_gemv2(
    const float* __restrict__ h, const float* __restrict__ Wl2, const float* __restrict__ Wr2,
    float* __restrict__ xl2, float* __restrict__ xr2, int N) {
    int t = threadIdx.x;
    int l = t & 63;
    int n = (blockIdx.x * 256 + t) >> 6;
    if (n >= N) return;
    float hv0 = h[(size_t)n * 128 + l];
    float hv1 = h[(size_t)n * 128 + 64 + l];
    float al[4], ar[4];
    #pragma unroll
    for (int c = 0; c < 4; ++c) {
        al[c] = hv0 * Wl2[l * 4 + c] + hv1 * Wl2[(64 + l) * 4 + c];
        ar[c] = hv0 * Wr2[l * 4 + c] + hv1 * Wr2[(64 + l) * 4 + c];
    }
    #pragma unroll
    for (int ms = 1; ms < 64; ms <<= 1) {
        #pragma unroll
        for (int c = 0; c < 4; ++c) {
            al[c] += __shfl_xor(al[c], ms);
            ar[c] += __shfl_xor(ar[c], ms);
        }
    }
    if (l == 0) {
        #pragma unroll
        for (int c = 0; c < 4; ++c) {
            xl2[(size_t)n * 4 + c] = al[c];
            xr2[(size_t)n * 4 + c] = ar[c];
        }
    }
}

// layer-2 logits per augmented edge (thread per edge)
__global__ __launch_bounds__(256) void k_logits2(
    const int* __restrict__ src, const int* __restrict__ dst,
    const float* __restrict__ edge_attr, const float* __restrict__ loop_attr,
    const float* __restrict__ xl2, const float* __restrict__ xr2,
    const float* __restrict__ We2, const float* __restrict__ att2,
    float* __restrict__ logits2, int E, int N) {
    int m = blockIdx.x * blockDim.x + threadIdx.x;
    int M = E + N;
    if (m >= M) return;
    int s, d;
    const float* ea;
    if (m < E) { s = src[m]; d = dst[m]; ea = edge_attr + (size_t)m * 16; }
    else       { s = d = m - E;          ea = loop_attr + (size_t)(m - E) * 16; }
    float v[4];
    #pragma unroll
    for (int c = 0; c < 4; ++c) v[c] = xl2[(size_t)s * 4 + c] + xr2[(size_t)d * 4 + c];
    const float4* ea4 = (const float4*)ea;
    float eav[16];
    #pragma unroll
    for (int q = 0; q < 4; ++q) {
        float4 e4 = ea4[q];
        eav[q * 4 + 0] = e4.x; eav[q * 4 + 1] = e4.y;
        eav[q * 4 + 2] = e4.z; eav[q * 4 + 3] = e4.w;
    }
    #pragma unroll
    for (int k = 0; k < 16; ++k) {
        #pragma unroll
        for (int c = 0; c < 4; ++c) v[c] += eav[k] * We2[k * 4 + c];
    }
    float4 out;
    float* ov = &out.x;
    #pragma unroll
    for (int c = 0; c < 4; ++c) {
        float e = v[c];
        e = e > 0.f ? e : 0.2f * e;
        ov[c] = e * att2[c];  // att2 is (4,1)
    }
    *(float4*)(&logits2[(size_t)m * 4]) = out;
}

// layer-2 per-node softmax + aggregation + head-mean -> final output
__global__ __launch_bounds__(256) void k_node2(
    const int* __restrict__ src, const int* __restrict__ rowptr, const int* __restrict__ csr,
    const float* __restrict__ logits2, const float* __restrict__ xl2,
    float* __restrict__ out, int E, int N) {
    int t = threadIdx.x;
    int l = t & 63;
    int n = (blockIdx.x * 256 + t) >> 6;
    if (n >= N) return;
    int rs = rowptr[n], re = rowptr[n + 1];
    int h = l & 3;
    int j0 = l >> 2;
    float selflg = logits2[(size_t)(E + n) * 4 + h];
    float mx = selflg;
    for (int j = rs + j0; j < re; j += 16)
        mx = fmaxf(mx, logits2[(size_t)csr[j] * 4 + h]);
    #pragma unroll
    for (int ms = 4; ms < 64; ms <<= 1) mx = fmaxf(mx, __shfl_xor(mx, ms));
    float sm = 0.f, acc = 0.f;
    if (j0 == 0) {
        float w = expf(selflg - mx);
        sm = w;
        acc = w * xl2[(size_t)n * 4 + h];
    }
    for (int j = rs + j0; j < re; j += 16) {
        int eid = csr[j];
        float w = expf(logits2[(size_t)eid * 4 + h] - mx);
        sm += w;
        acc += w * xl2[(size_t)src[eid] * 4 + h];
    }
    #pragma unroll
    for (int ms = 4; ms < 64; ms <<= 1) {
        sm += __shfl_xor(sm, ms);
        acc += __shfl_xor(acc, ms);
    }
    float val = acc / (sm + 1e-16f);
    val += __shfl_xor(val, 1);  // mean over the 4 heads
    val += __shfl_xor(val, 2);
    if (l == 0) out[n] = val * 0.25f;
}

extern "C" void kernel_launch(void* const* d_in, const int* in_sizes, int n_in,
                              void* d_out, int out_size, void* d_ws, size_t ws_size,
                              hipStream_t stream) {
    const float* x         = (const float*)d_in[0];
    const int*   edge_index= (const int*)d_in[1];
    const float* edge_attr = (const float*)d_in[2];
    const float* Wl1       = (const float*)d_in[3];
    const float* Wr1       = (const float*)d_in[4];
    const float* We1       = (const float*)d_in[5];
    const float* att1      = (const float*)d_in[6];
    const float* Wl2       = (const float*)d_in[7];
    const float* Wr2       = (const float*)d_in[8];
    const float* We2       = (const float*)d_in[9];
    const float* att2      = (const float*)d_in[10];
    float* outp = (float*)d_out;

    const int F = 128, HC = 128, EDIM = 16;
    int N = in_sizes[0] / F;
    int E = in_sizes[1] / 2;
    int M = E + N;
    const int* src = edge_index;
    const int* dst = edge_index + E;

    char* ws = (char*)d_ws;
    size_t off = 0;
    auto alloc = [&](size_t bytes) {
        char* p = ws + off;
        off += (bytes + 255) & ~(size_t)255;
        return p;
    };
    int*   deg      = (int*)alloc((size_t)N * 4);
    int*   rowptr   = (int*)alloc((size_t)(N + 1) * 4);
    int*   cursor   = (int*)alloc((size_t)N * 4);
    int*   csr      = (int*)alloc((size_t)E * 4);
    float* loop_attr= (float*)alloc((size_t)N * EDIM * 4);
    float* xl1      = (float*)alloc((size_t)N * HC * 4);
    float* xr1      = (float*)alloc((size_t)N * HC * 4);
    float* logits1  = (float*)alloc((size_t)M * 4 * 4);
    float* xl2      = (float*)alloc((size_t)N * 4 * 4);
    float* xr2      = (float*)alloc((size_t)N * 4 * 4);
    // aliases (stream-ordered; xr1 dead after k_logits1, logits1 dead after k_node1)
    float* hbuf    = xr1;
    float* logits2 = logits1;

    hipMemsetAsync(deg, 0, (size_t)N * 4, stream);
    hipMemsetAsync(cursor, 0, (size_t)N * 4, stream);

    int eb = (E + 255) / 256;
    k_count_deg<<<eb, 256, 0, stream>>>(dst, deg, E);
    k_scan<<<1, 1024, 0, stream>>>(deg, rowptr, N);
    k_scatter<<<eb, 256, 0, stream>>>(dst, rowptr, cursor, csr, E);
    k_loop_attr<<<(N * 16 + 255) / 256, 256, 0, stream>>>(edge_attr, rowptr, csr, loop_attr, N);
    k_gemm1<<<(N + 31) / 32, 256, 0, stream>>>(x, Wl1, Wr1, xl1, xr1, N);
    k_logits1<<<(M + 3) / 4, 256, 0, stream>>>(src, dst, edge_attr, loop_attr,
                                               xl1, xr1, We1, att1, logits1, E, N);
    k_node1<<<(N + 3) / 4, 256, 0, stream>>>(src, rowptr, csr, logits1, xl1, hbuf, E, N);
    k_gemv2<<<(N + 3) / 4, 256, 0, stream>>>(hbuf, Wl2, Wr2, xl2, xr2, N);
    k_logits2<<<(M + 255) / 256, 256, 0, stream>>>(src, dst, edge_attr, loop_attr,
                                                   xl2, xr2, We2, att2, logits2, E, N);
    k_node2<<<(N + 3) / 4, 256, 0, stream>>>(src, rowptr, csr, logits2, xl2, outp, E, N);
}

// Round 2
// 567.215 us; speedup vs baseline: 1.5333x; 1.5333x over previous
//
#include <hip/hip_runtime.h>
#include <math.h>

// ---------------------------------------------------------------------------
// GATv2 x2 on MI355X. Fused one-pass-softmax structure:
//   memset -> count_deg -> scan -> scatter(CSR) -> gemm1(xl bf16, xr f32)
//   -> permute(ea->CSR order f32, qe2 = ea@We2) -> loopq(loop_attr, qself2)
//   -> fused1(logits+softmax+aggregate+lrelu+gemv2 -> xl2,xr2)
//   -> fused2(logits2+softmax+aggregate+head-mean -> out)
// One-pass softmax: alpha = exp(l)/sum(exp(l)) == ref's exp(l-lmax)/sum(...).
// ---------------------------------------------------------------------------

static __device__ __forceinline__ ushort f2bf(float f) {
    unsigned u = __float_as_uint(f);
    unsigned r = (u + 0x7fffu + ((u >> 16) & 1u)) >> 16;  // RNE
    return (ushort)r;
}

__global__ void k_count_deg(const int* __restrict__ dst, int* __restrict__ deg, int E) {
    int i = blockIdx.x * blockDim.x + threadIdx.x;
    if (i < E) atomicAdd(&deg[dst[i]], 1);
}

// single-block exclusive scan of deg -> rowptr
__global__ __launch_bounds__(1024) void k_scan(const int* __restrict__ deg,
                                               int* __restrict__ rowptr, int N) {
    __shared__ int wsum[16];
    __shared__ int s_run;
    int t = threadIdx.x;
    int l = t & 63;
    int w = t >> 6;
    if (t == 0) s_run = 0;
    __syncthreads();
    for (int base = 0; base < N; base += 1024) {
        int i = base + t;
        int v = (i < N) ? deg[i] : 0;
        int sc = v;
        #pragma unroll
        for (int off = 1; off < 64; off <<= 1) {
            int y = __shfl_up(sc, off);
            if (l >= off) sc += y;
        }
        if (l == 63) wsum[w] = sc;
        __syncthreads();
        if (w == 0) {
            int pv = (l < 16) ? wsum[l] : 0;
            int psc = pv;
            #pragma unroll
            for (int off = 1; off < 16; off <<= 1) {
                int y = __shfl_up(psc, off);
                if (l >= off) psc += y;
            }
            if (l < 16) wsum[l] = psc - pv;
        }
        __syncthreads();
        if (i < N) rowptr[i] = s_run + wsum[w] + sc - v;
        __syncthreads();
        if (t == 1023) s_run += wsum[15] + sc;
        __syncthreads();
    }
    if (t == 0) rowptr[N] = s_run;
}

__global__ void k_scatter(const int* __restrict__ dst, const int* __restrict__ rowptr,
                          int* __restrict__ cursor, int* __restrict__ csr, int E) {
    int i = blockIdx.x * blockDim.x + threadIdx.x;
    if (i < E) {
        int d = dst[i];
        int pos = rowptr[d] + atomicAdd(&cursor[d], 1);
        csr[pos] = i;
    }
}

// xl1 = x @ Wl1 (bf16 out), xr1 = x @ Wr1 (f32 out)
__global__ __launch_bounds__(256) void k_gemm1(const float* __restrict__ x,
                                               const float* __restrict__ Wl,
                                               const float* __restrict__ Wr,
                                               ushort* __restrict__ xl, float* __restrict__ xr,
                                               int N) {
    __shared__ float xs[32 * 128];
    int r0 = blockIdx.x * 32;
    int t = threadIdx.x;
    for (int i = t * 4; i < 32 * 128; i += 256 * 4) {
        int r = i >> 7;
        float4 v = make_float4(0.f, 0.f, 0.f, 0.f);
        if (r0 + r < N) v = *(const float4*)(&x[(size_t)(r0 + r) * 128 + (i & 127)]);
        *(float4*)(&xs[i]) = v;
    }
    __syncthreads();
    int c = t & 127;
    int rbase = (t >> 7) * 16;  // 0 or 16
    float accl[16], accr[16];
    #pragma unroll
    for (int r = 0; r < 16; ++r) { accl[r] = 0.f; accr[r] = 0.f; }
    for (int k = 0; k < 128; ++k) {
        float wl = Wl[k * 128 + c];
        float wr = Wr[k * 128 + c];
        #pragma unroll
        for (int r = 0; r < 16; ++r) {
            float xv = xs[(rbase + r) * 128 + k];
            accl[r] += xv * wl;
            accr[r] += xv * wr;
        }
    }
    #pragma unroll
    for (int r = 0; r < 16; ++r) {
        int row = r0 + rbase + r;
        if (row < N) {
            xl[(size_t)row * 128 + c] = f2bf(accl[r]);
            xr[(size_t)row * 128 + c] = accr[r];
        }
    }
}

// permute edge_attr into CSR order (f32) and precompute qe2 = ea @ We2 (E x 4)
__global__ __launch_bounds__(256) void k_permute(const int* __restrict__ csr,
                                                 const float* __restrict__ ea,
                                                 const float* __restrict__ We2,
                                                 float* __restrict__ ea_perm,
                                                 float* __restrict__ qe2, int E) {
    __shared__ float sW[64];
    int t = threadIdx.x;
    if (t < 64) sW[t] = We2[t];
    __syncthreads();
    int j = blockIdx.x * 256 + t;
    if (j >= E) return;
    int e = csr[j];
    const float4* s4 = (const float4*)(ea + (size_t)e * 16);
    float4* d4 = (float4*)(ea_perm + (size_t)j * 16);
    float q0 = 0.f, q1 = 0.f, q2 = 0.f, q3 = 0.f;
    #pragma unroll
    for (int b = 0; b < 4; ++b) {
        float4 v = s4[b];
        d4[b] = v;
        int k = 4 * b;
        q0 += v.x * sW[k * 4 + 0] + v.y * sW[(k + 1) * 4 + 0] + v.z * sW[(k + 2) * 4 + 0] + v.w * sW[(k + 3) * 4 + 0];
        q1 += v.x * sW[k * 4 + 1] + v.y * sW[(k + 1) * 4 + 1] + v.z * sW[(k + 2) * 4 + 1] + v.w * sW[(k + 3) * 4 + 1];
        q2 += v.x * sW[k * 4 + 2] + v.y * sW[(k + 1) * 4 + 2] + v.z * sW[(k + 2) * 4 + 2] + v.w * sW[(k + 3) * 4 + 2];
        q3 += v.x * sW[k * 4 + 3] + v.y * sW[(k + 1) * 4 + 3] + v.z * sW[(k + 2) * 4 + 3] + v.w * sW[(k + 3) * 4 + 3];
    }
    *(float4*)(qe2 + (size_t)j * 4) = make_float4(q0, q1, q2, q3);
}

// loop_attr[n] = mean incoming ea (f32); qself2[n] = mean incoming qe2
__global__ __launch_bounds__(256) void k_loopq(const float* __restrict__ ea_perm,
                                               const float* __restrict__ qe2,
                                               const int* __restrict__ rowptr,
                                               float* __restrict__ loop_attr,
                                               float* __restrict__ qself2, int N) {
    int idx = blockIdx.x * 256 + threadIdx.x;
    int tot1 = N * 16;
    if (idx < tot1) {
        int n = idx >> 4, k = idx & 15;
        int rs = rowptr[n], re = rowptr[n + 1];
        float s = 0.f;
        for (int j = rs; j < re; ++j) s += ea_perm[(size_t)j * 16 + k];
        int dg = re - rs;
        loop_attr[idx] = s / (float)(dg > 1 ? dg : 1);
    } else if (idx < tot1 + N * 4) {
        int i2 = idx - tot1;
        int n = i2 >> 2, c = i2 & 3;
        int rs = rowptr[n], re = rowptr[n + 1];
        float s = 0.f;
        for (int j = rs; j < re; ++j) s += qe2[(size_t)j * 4 + c];
        int dg = re - rs;
        qself2[i2] = s / (float)(dg > 1 ? dg : 1);
    }
}

// layer 1 fused: per node (wave per node, lane l owns channels 2l,2l+1):
// one-pass: w=exp(logit), acc += w*xl[s], den += w; h = lrelu(acc/den);
// epilogue: xl2 = h@Wl2, xr2 = h@Wr2 (cross-wave reduce)
__global__ __launch_bounds__(256) void k_fused1(
    const int* __restrict__ src, const int* __restrict__ rowptr, const int* __restrict__ csr,
    const ushort* __restrict__ xl_bf, const float* __restrict__ xr,
    const float* __restrict__ ea_perm, const float* __restrict__ loop_attr,
    const float* __restrict__ We, const float* __restrict__ att,
    const float* __restrict__ Wl2, const float* __restrict__ Wr2,
    float* __restrict__ xl2, float* __restrict__ xr2, int N) {
    int t = threadIdx.x;
    int l = t & 63;
    int n = (blockIdx.x * 256 + t) >> 6;
    if (n >= N) return;
    float we0[16], we1[16];
    #pragma unroll
    for (int k = 0; k < 16; ++k) {
        float2 w = *(const float2*)(We + k * 128 + 2 * l);
        we0[k] = w.x; we1[k] = w.y;
    }
    float2 av  = *(const float2*)(att + 2 * l);
    float2 xrv = *(const float2*)(xr + (size_t)n * 128 + 2 * l);
    int rs = rowptr[n], re = rowptr[n + 1];
    int deg = re - rs;
    float acc0 = 0.f, acc1 = 0.f, den = 0.f;
    // stage slot 0
    int s_nxt;
    const float4* ea_nxt;
    if (deg > 0) {
        int eid = csr[rs];
        s_nxt = src[eid];
        ea_nxt = (const float4*)(ea_perm + (size_t)rs * 16);
    } else {
        s_nxt = n;
        ea_nxt = (const float4*)(loop_attr + (size_t)n * 16);
    }
    for (int slot = 0; slot <= deg; ++slot) {
        int s = s_nxt;
        const float4* ea4 = ea_nxt;
        unsigned xw = *(const unsigned*)(xl_bf + (size_t)s * 128 + 2 * l);  // issue gather early
        int ns = slot + 1;
        if (ns <= deg) {  // stage next
            if (ns < deg) {
                int eid = csr[rs + ns];
                s_nxt = src[eid];
                ea_nxt = (const float4*)(ea_perm + (size_t)(rs + ns) * 16);
            } else {
                s_nxt = n;
                ea_nxt = (const float4*)(loop_attr + (size_t)n * 16);
            }
        }
        float v0 = xrv.x, v1 = xrv.y;
        #pragma unroll
        for (int b = 0; b < 4; ++b) {
            float4 a = ea4[b];
            v0 += a.x * we0[4*b] + a.y * we0[4*b+1] + a.z * we0[4*b+2] + a.w * we0[4*b+3];
            v1 += a.x * we1[4*b] + a.y * we1[4*b+1] + a.z * we1[4*b+2] + a.w * we1[4*b+3];
        }
        float xl0 = __uint_as_float(xw << 16);
        float xl1 = __uint_as_float(xw & 0xffff0000u);
        v0 += xl0; v1 += xl1;
        v0 = v0 > 0.f ? v0 : 0.2f * v0;
        v1 = v1 > 0.f ? v1 : 0.2f * v1;
        float p = av.x * v0 + av.y * v1;
        p += __shfl_xor(p, 1);
        p += __shfl_xor(p, 2);
        p += __shfl_xor(p, 4);
        p += __shfl_xor(p, 8);  // head logit (head = l>>4, lanes [16h,16h+16))
        float w = __expf(p);
        acc0 += w * xl0;
        acc1 += w * xl1;
        den  += w;
    }
    float rdn = 1.f / (den + 1e-16f);
    float h0 = acc0 * rdn, h1 = acc1 * rdn;
    h0 = h0 > 0.f ? h0 : 0.01f * h0;
    h1 = h1 > 0.f ? h1 : 0.01f * h1;
    float4 wla = *(const float4*)(Wl2 + (size_t)(2 * l) * 4);
    float4 wlb = *(const float4*)(Wl2 + (size_t)(2 * l + 1) * 4);
    float4 wra = *(const float4*)(Wr2 + (size_t)(2 * l) * 4);
    float4 wrb = *(const float4*)(Wr2 + (size_t)(2 * l + 1) * 4);
    float q0 = h0 * wla.x + h1 * wlb.x;
    float q1 = h0 * wla.y + h1 * wlb.y;
    float q2 = h0 * wla.z + h1 * wlb.z;
    float q3 = h0 * wla.w + h1 * wlb.w;
    float q4 = h0 * wra.x + h1 * wrb.x;
    float q5 = h0 * wra.y + h1 * wrb.y;
    float q6 = h0 * wra.z + h1 * wrb.z;
    float q7 = h0 * wra.w + h1 * wrb.w;
    #pragma unroll
    for (int ms = 1; ms < 64; ms <<= 1) {
        q0 += __shfl_xor(q0, ms); q1 += __shfl_xor(q1, ms);
        q2 += __shfl_xor(q2, ms); q3 += __shfl_xor(q3, ms);
        q4 += __shfl_xor(q4, ms); q5 += __shfl_xor(q5, ms);
        q6 += __shfl_xor(q6, ms); q7 += __shfl_xor(q7, ms);
    }
    if (l == 0) {
        *(float4*)(xl2 + (size_t)n * 4) = make_float4(q0, q1, q2, q3);
        *(float4*)(xr2 + (size_t)n * 4) = make_float4(q4, q5, q6, q7);
    }
}

// layer 2 fused: 16 lanes per node (4 nodes per wave), one-pass softmax + head-mean
__global__ __launch_bounds__(256) void k_fused2(
    const int* __restrict__ src, const int* __restrict__ rowptr, const int* __restrict__ csr,
    const float* __restrict__ xl2, const float* __restrict__ xr2,
    const float* __restrict__ qe2, const float* __restrict__ qself2,
    const float* __restrict__ att2, float* __restrict__ out, int N) {
    int t = threadIdx.x;
    int l = t & 63;
    int g = l & 15;
    int node = (((blockIdx.x * 256 + t) >> 6) << 2) + (l >> 4);
    if (node >= N) return;
    int rs = rowptr[node], re = rowptr[node + 1];
    int deg = re - rs;
    float4 xrv = *(const float4*)(xr2 + (size_t)node * 4);
    float a0 = att2[0], a1 = att2[1], a2 = att2[2], a3 = att2[3];
    float ac0 = 0.f, ac1 = 0.f, ac2 = 0.f, ac3 = 0.f;
    float dn0 = 0.f, dn1 = 0.f, dn2 = 0.f, dn3 = 0.f;
    for (int slot = g; slot <= deg; slot += 16) {
        int s;
        float4 q;
        if (slot < deg) {
            int j = rs + slot;
            int eid = csr[j];
            s = src[eid];
            q = *(const float4*)(qe2 + (size_t)j * 4);
        } else {
            s = node;
            q = *(const float4*)(qself2 + (size_t)node * 4);
        }
        float4 xv = *(const float4*)(xl2 + (size_t)s * 4);
        float v0 = xv.x + xrv.x + q.x; v0 = v0 > 0.f ? v0 : 0.2f * v0;
        float v1 = xv.y + xrv.y + q.y; v1 = v1 > 0.f ? v1 : 0.2f * v1;
        float v2 = xv.z + xrv.z + q.z; v2 = v2 > 0.f ? v2 : 0.2f * v2;
        float v3 = xv.w + xrv.w + q.w; v3 = v3 > 0.f ? v3 : 0.2f * v3;
        float w0 = __expf(v0 * a0); ac0 += w0 * xv.x; dn0 += w0;
        float w1 = __expf(v1 * a1); ac1 += w1 * xv.y; dn1 += w1;
        float w2 = __expf(v2 * a2); ac2 += w2 * xv.z; dn2 += w2;
        float w3 = __expf(v3 * a3); ac3 += w3 * xv.w; dn3 += w3;
    }
    #pragma unroll
    for (int ms = 1; ms < 16; ms <<= 1) {
        ac0 += __shfl_xor(ac0, ms); ac1 += __shfl_xor(ac1, ms);
        ac2 += __shfl_xor(ac2, ms); ac3 += __shfl_xor(ac3, ms);
        dn0 += __shfl_xor(dn0, ms); dn1 += __shfl_xor(dn1, ms);
        dn2 += __shfl_xor(dn2, ms); dn3 += __shfl_xor(dn3, ms);
    }
    if (g == 0) {
        float r = ac0 / (dn0 + 1e-16f) + ac1 / (dn1 + 1e-16f)
                + ac2 / (dn2 + 1e-16f) + ac3 / (dn3 + 1e-16f);
        out[node] = r * 0.25f;
    }
}

extern "C" void kernel_launch(void* const* d_in, const int* in_sizes, int n_in,
                              void* d_out, int out_size, void* d_ws, size_t ws_size,
                              hipStream_t stream) {
    const float* x         = (const float*)d_in[0];
    const int*   edge_index= (const int*)d_in[1];
    const float* edge_attr = (const float*)d_in[2];
    const float* Wl1       = (const float*)d_in[3];
    const float* Wr1       = (const float*)d_in[4];
    const float* We1       = (const float*)d_in[5];
    const float* att1      = (const float*)d_in[6];
    const float* Wl2       = (const float*)d_in[7];
    const float* Wr2       = (const float*)d_in[8];
    const float* We2       = (const float*)d_in[9];
    const float* att2      = (const float*)d_in[10];
    float* outp = (float*)d_out;

    const int F = 128, HC = 128, EDIM = 16;
    int N = in_sizes[0] / F;
    int E = in_sizes[1] / 2;
    const int* src = edge_index;
    const int* dst = edge_index + E;

    char* ws = (char*)d_ws;
    size_t off = 0;
    auto alloc = [&](size_t bytes) {
        char* p = ws + off;
        off += (bytes + 255) & ~(size_t)255;
        return p;
    };
    int*    deg      = (int*)alloc((size_t)N * 4);
    int*    rowptr   = (int*)alloc((size_t)(N + 1) * 4);
    int*    cursor   = (int*)alloc((size_t)N * 4);
    int*    csr      = (int*)alloc((size_t)E * 4);
    float*  ea_perm  = (float*)alloc((size_t)E * EDIM * 4);
    float*  qe2      = (float*)alloc((size_t)E * 4 * 4);
    float*  loop_attr= (float*)alloc((size_t)N * EDIM * 4);
    float*  qself2   = (float*)alloc((size_t)N * 4 * 4);
    ushort* xl_bf    = (ushort*)alloc((size_t)N * HC * 2);
    float*  xr1      = (float*)alloc((size_t)N * HC * 4);
    float*  xl2      = (float*)alloc((size_t)N * 4 * 4);
    float*  xr2      = (float*)alloc((size_t)N * 4 * 4);

    hipMemsetAsync(deg, 0, (size_t)N * 4, stream);
    hipMemsetAsync(cursor, 0, (size_t)N * 4, stream);

    int eb = (E + 255) / 256;
    k_count_deg<<<eb, 256, 0, stream>>>(dst, deg, E);
    k_scan<<<1, 1024, 0, stream>>>(deg, rowptr, N);
    k_scatter<<<eb, 256, 0, stream>>>(dst, rowptr, cursor, csr, E);
    k_gemm1<<<(N + 31) / 32, 256, 0, stream>>>(x, Wl1, Wr1, xl_bf, xr1, N);
    k_permute<<<eb, 256, 0, stream>>>(csr, edge_attr, We2, ea_perm, qe2, E);
    k_loopq<<<(N * 20 + 255) / 256, 256, 0, stream>>>(ea_perm, qe2, rowptr, loop_attr, qself2, N);
    k_fused1<<<(N + 3) / 4, 256, 0, stream>>>(src, rowptr, csr, xl_bf, xr1, ea_perm, loop_attr,
                                              We1, att1, Wl2, Wr2, xl2, xr2, N);
    k_fused2<<<(N + 15) / 16, 256, 0, stream>>>(src, rowptr, csr, xl2, xr2, qe2, qself2,
                                                att2, outp, N);
}

// Round 3
// 550.518 us; speedup vs baseline: 1.5798x; 1.0303x over previous
//
#include <hip/hip_runtime.h>
#include <math.h>

// ---------------------------------------------------------------------------
// GATv2 x2 on MI355X. Fused one-pass-softmax structure:
//   memset -> count_deg -> scan -> scatter(CSR) -> gemm1(xl bf16, xr f32)
//   -> permute(ea->CSR order f32, qe2 = ea@We2) -> loopq(loop_attr, qself2)
//   -> fused1(logits+softmax+aggregate+lrelu+gemv2 -> xl2,xr2)  [unroll-2 + DPP]
//   -> fused2(logits2+softmax+aggregate+head-mean -> out)       [DPP]
// ---------------------------------------------------------------------------

static __device__ __forceinline__ ushort f2bf(float f) {
    unsigned u = __float_as_uint(f);
    unsigned r = (u + 0x7fffu + ((u >> 16) & 1u)) >> 16;  // RNE
    return (ushort)r;
}

// sum across each 16-lane row via DPP row_ror (pure VALU, no DS)
static __device__ __forceinline__ float row_sum16(float x) {
    x += __int_as_float(__builtin_amdgcn_update_dpp(0, __float_as_int(x), 0x121, 0xf, 0xf, true));
    x += __int_as_float(__builtin_amdgcn_update_dpp(0, __float_as_int(x), 0x122, 0xf, 0xf, true));
    x += __int_as_float(__builtin_amdgcn_update_dpp(0, __float_as_int(x), 0x124, 0xf, 0xf, true));
    x += __int_as_float(__builtin_amdgcn_update_dpp(0, __float_as_int(x), 0x128, 0xf, 0xf, true));
    return x;
}

static __device__ __forceinline__ float red64(float x) {  // 64-lane sum
    x = row_sum16(x);
    x += __shfl_xor(x, 16);
    x += __shfl_xor(x, 32);
    return x;
}

__global__ void k_count_deg(const int* __restrict__ dst, int* __restrict__ deg, int E) {
    int i = blockIdx.x * blockDim.x + threadIdx.x;
    if (i < E) atomicAdd(&deg[dst[i]], 1);
}

// single-block exclusive scan of deg -> rowptr
__global__ __launch_bounds__(1024) void k_scan(const int* __restrict__ deg,
                                               int* __restrict__ rowptr, int N) {
    __shared__ int wsum[16];
    __shared__ int s_run;
    int t = threadIdx.x;
    int l = t & 63;
    int w = t >> 6;
    if (t == 0) s_run = 0;
    __syncthreads();
    for (int base = 0; base < N; base += 1024) {
        int i = base + t;
        int v = (i < N) ? deg[i] : 0;
        int sc = v;
        #pragma unroll
        for (int off = 1; off < 64; off <<= 1) {
            int y = __shfl_up(sc, off);
            if (l >= off) sc += y;
        }
        if (l == 63) wsum[w] = sc;
        __syncthreads();
        if (w == 0) {
            int pv = (l < 16) ? wsum[l] : 0;
            int psc = pv;
            #pragma unroll
            for (int off = 1; off < 16; off <<= 1) {
                int y = __shfl_up(psc, off);
                if (l >= off) psc += y;
            }
            if (l < 16) wsum[l] = psc - pv;
        }
        __syncthreads();
        if (i < N) rowptr[i] = s_run + wsum[w] + sc - v;
        __syncthreads();
        if (t == 1023) s_run += wsum[15] + sc;
        __syncthreads();
    }
    if (t == 0) rowptr[N] = s_run;
}

__global__ void k_scatter(const int* __restrict__ dst, const int* __restrict__ rowptr,
                          int* __restrict__ cursor, int* __restrict__ csr, int E) {
    int i = blockIdx.x * blockDim.x + threadIdx.x;
    if (i < E) {
        int d = dst[i];
        int pos = rowptr[d] + atomicAdd(&cursor[d], 1);
        csr[pos] = i;
    }
}

// xl1 = x @ Wl1 (bf16 out), xr1 = x @ Wr1 (f32 out)
__global__ __launch_bounds__(256) void k_gemm1(const float* __restrict__ x,
                                               const float* __restrict__ Wl,
                                               const float* __restrict__ Wr,
                                               ushort* __restrict__ xl, float* __restrict__ xr,
                                               int N) {
    __shared__ float xs[32 * 128];
    int r0 = blockIdx.x * 32;
    int t = threadIdx.x;
    for (int i = t * 4; i < 32 * 128; i += 256 * 4) {
        int r = i >> 7;
        float4 v = make_float4(0.f, 0.f, 0.f, 0.f);
        if (r0 + r < N) v = *(const float4*)(&x[(size_t)(r0 + r) * 128 + (i & 127)]);
        *(float4*)(&xs[i]) = v;
    }
    __syncthreads();
    int c = t & 127;
    int rbase = (t >> 7) * 16;  // 0 or 16
    float accl[16], accr[16];
    #pragma unroll
    for (int r = 0; r < 16; ++r) { accl[r] = 0.f; accr[r] = 0.f; }
    for (int k = 0; k < 128; ++k) {
        float wl = Wl[k * 128 + c];
        float wr = Wr[k * 128 + c];
        #pragma unroll
        for (int r = 0; r < 16; ++r) {
            float xv = xs[(rbase + r) * 128 + k];
            accl[r] += xv * wl;
            accr[r] += xv * wr;
        }
    }
    #pragma unroll
    for (int r = 0; r < 16; ++r) {
        int row = r0 + rbase + r;
        if (row < N) {
            xl[(size_t)row * 128 + c] = f2bf(accl[r]);
            xr[(size_t)row * 128 + c] = accr[r];
        }
    }
}

// permute edge_attr into CSR order (f32) and precompute qe2 = ea @ We2 (E x 4)
__global__ __launch_bounds__(256) void k_permute(const int* __restrict__ csr,
                                                 const float* __restrict__ ea,
                                                 const float* __restrict__ We2,
                                                 float* __restrict__ ea_perm,
                                                 float* __restrict__ qe2, int E) {
    __shared__ float sW[64];
    int t = threadIdx.x;
    if (t < 64) sW[t] = We2[t];
    __syncthreads();
    int j = blockIdx.x * 256 + t;
    if (j >= E) return;
    int e = csr[j];
    const float4* s4 = (const float4*)(ea + (size_t)e * 16);
    float4* d4 = (float4*)(ea_perm + (size_t)j * 16);
    float q0 = 0.f, q1 = 0.f, q2 = 0.f, q3 = 0.f;
    #pragma unroll
    for (int b = 0; b < 4; ++b) {
        float4 v = s4[b];
        d4[b] = v;
        int k = 4 * b;
        q0 += v.x * sW[k * 4 + 0] + v.y * sW[(k + 1) * 4 + 0] + v.z * sW[(k + 2) * 4 + 0] + v.w * sW[(k + 3) * 4 + 0];
        q1 += v.x * sW[k * 4 + 1] + v.y * sW[(k + 1) * 4 + 1] + v.z * sW[(k + 2) * 4 + 1] + v.w * sW[(k + 3) * 4 + 1];
        q2 += v.x * sW[k * 4 + 2] + v.y * sW[(k + 1) * 4 + 2] + v.z * sW[(k + 2) * 4 + 2] + v.w * sW[(k + 3) * 4 + 2];
        q3 += v.x * sW[k * 4 + 3] + v.y * sW[(k + 1) * 4 + 3] + v.z * sW[(k + 2) * 4 + 3] + v.w * sW[(k + 3) * 4 + 3];
    }
    *(float4*)(qe2 + (size_t)j * 4) = make_float4(q0, q1, q2, q3);
}

// loop_attr[n] = mean incoming ea (f32); qself2[n] = mean incoming qe2
__global__ __launch_bounds__(256) void k_loopq(const float* __restrict__ ea_perm,
                                               const float* __restrict__ qe2,
                                               const int* __restrict__ rowptr,
                                               float* __restrict__ loop_attr,
                                               float* __restrict__ qself2, int N) {
    int idx = blockIdx.x * 256 + threadIdx.x;
    int tot1 = N * 16;
    if (idx < tot1) {
        int n = idx >> 4, k = idx & 15;
        int rs = rowptr[n], re = rowptr[n + 1];
        float s = 0.f;
        for (int j = rs; j < re; ++j) s += ea_perm[(size_t)j * 16 + k];
        int dg = re - rs;
        loop_attr[idx] = s / (float)(dg > 1 ? dg : 1);
    } else if (idx < tot1 + N * 4) {
        int i2 = idx - tot1;
        int n = i2 >> 2, c = i2 & 3;
        int rs = rowptr[n], re = rowptr[n + 1];
        float s = 0.f;
        for (int j = rs; j < re; ++j) s += qe2[(size_t)j * 4 + c];
        int dg = re - rs;
        qself2[i2] = s / (float)(dg > 1 ? dg : 1);
    }
}

// layer 1 fused (wave per node, lane l owns channels 2l,2l+1), slot loop unroll-2
__global__ __launch_bounds__(256) void k_fused1(
    const int* __restrict__ src, const int* __restrict__ rowptr, const int* __restrict__ csr,
    const ushort* __restrict__ xl_bf, const float* __restrict__ xr,
    const float* __restrict__ ea_perm, const float* __restrict__ loop_attr,
    const float* __restrict__ We, const float* __restrict__ att,
    const float* __restrict__ Wl2, const float* __restrict__ Wr2,
    float* __restrict__ xl2, float* __restrict__ xr2, int N) {
    int t = threadIdx.x;
    int l = t & 63;
    int n = (blockIdx.x * 256 + t) >> 6;
    if (n >= N) return;
    float we0[16], we1[16];
    #pragma unroll
    for (int k = 0; k < 16; ++k) {
        float2 w = *(const float2*)(We + k * 128 + 2 * l);
        we0[k] = w.x; we1[k] = w.y;
    }
    float2 av  = *(const float2*)(att + 2 * l);
    float2 xrv = *(const float2*)(xr + (size_t)n * 128 + 2 * l);
    int rs = rowptr[n], re = rowptr[n + 1];
    int deg = re - rs;
    int nslots = deg + 1;  // + self loop (last slot)
    float acc0 = 0.f, acc1 = 0.f, den = 0.f;
    for (int slot = 0; slot < nslots; slot += 2) {
        int s0, s1;
        const float4 *p0, *p1;
        if (slot < deg) {
            int e = csr[rs + slot];
            s0 = src[e];
            p0 = (const float4*)(ea_perm + (size_t)(rs + slot) * 16);
        } else {
            s0 = n;
            p0 = (const float4*)(loop_attr + (size_t)n * 16);
        }
        bool has1 = (slot + 1) < nslots;
        int sl1 = has1 ? (slot + 1) : slot;  // duplicate last slot; weight masked
        if (sl1 < deg) {
            int e = csr[rs + sl1];
            s1 = src[e];
            p1 = (const float4*)(ea_perm + (size_t)(rs + sl1) * 16);
        } else {
            s1 = n;
            p1 = (const float4*)(loop_attr + (size_t)n * 16);
        }
        // issue all loads up front (independent)
        unsigned xw0 = *(const unsigned*)(xl_bf + (size_t)s0 * 128 + 2 * l);
        unsigned xw1 = *(const unsigned*)(xl_bf + (size_t)s1 * 128 + 2 * l);
        float4 a00 = p0[0], a01 = p0[1], a02 = p0[2], a03 = p0[3];
        float4 a10 = p1[0], a11 = p1[1], a12 = p1[2], a13 = p1[3];
        // chain 0
        float v00 = xrv.x, v01 = xrv.y;
        v00 += a00.x*we0[0] + a00.y*we0[1] + a00.z*we0[2] + a00.w*we0[3]
             + a01.x*we0[4] + a01.y*we0[5] + a01.z*we0[6] + a01.w*we0[7]
             + a02.x*we0[8] + a02.y*we0[9] + a02.z*we0[10] + a02.w*we0[11]
             + a03.x*we0[12] + a03.y*we0[13] + a03.z*we0[14] + a03.w*we0[15];
        v01 += a00.x*we1[0] + a00.y*we1[1] + a00.z*we1[2] + a00.w*we1[3]
             + a01.x*we1[4] + a01.y*we1[5] + a01.z*we1[6] + a01.w*we1[7]
             + a02.x*we1[8] + a02.y*we1[9] + a02.z*we1[10] + a02.w*we1[11]
             + a03.x*we1[12] + a03.y*we1[13] + a03.z*we1[14] + a03.w*we1[15];
        float xl00 = __uint_as_float(xw0 << 16);
        float xl01 = __uint_as_float(xw0 & 0xffff0000u);
        v00 += xl00; v01 += xl01;
        v00 = v00 > 0.f ? v00 : 0.2f * v00;
        v01 = v01 > 0.f ? v01 : 0.2f * v01;
        float pa = row_sum16(av.x * v00 + av.y * v01);
        float wa = __expf(pa);
        // chain 1
        float v10 = xrv.x, v11 = xrv.y;
        v10 += a10.x*we0[0] + a10.y*we0[1] + a10.z*we0[2] + a10.w*we0[3]
             + a11.x*we0[4] + a11.y*we0[5] + a11.z*we0[6] + a11.w*we0[7]
             + a12.x*we0[8] + a12.y*we0[9] + a12.z*we0[10] + a12.w*we0[11]
             + a13.x*we0[12] + a13.y*we0[13] + a13.z*we0[14] + a13.w*we0[15];
        float v11b = a10.x*we1[0] + a10.y*we1[1] + a10.z*we1[2] + a10.w*we1[3]
             + a11.x*we1[4] + a11.y*we1[5] + a11.z*we1[6] + a11.w*we1[7]
             + a12.x*we1[8] + a12.y*we1[9] + a12.z*we1[10] + a12.w*we1[11]
             + a13.x*we1[12] + a13.y*we1[13] + a13.z*we1[14] + a13.w*we1[15];
        v11 += v11b;
        float xl10 = __uint_as_float(xw1 << 16);
        float xl11 = __uint_as_float(xw1 & 0xffff0000u);
        v10 += xl10; v11 += xl11;
        v10 = v10 > 0.f ? v10 : 0.2f * v10;
        v11 = v11 > 0.f ? v11 : 0.2f * v11;
        float pb = row_sum16(av.x * v10 + av.y * v11);
        float wb = __expf(pb) * (has1 ? 1.f : 0.f);
        // accumulate
        acc0 += wa * xl00 + wb * xl10;
        acc1 += wa * xl01 + wb * xl11;
        den  += wa + wb;
    }
    float rdn = 1.f / (den + 1e-16f);
    float h0 = acc0 * rdn, h1 = acc1 * rdn;
    h0 = h0 > 0.f ? h0 : 0.01f * h0;
    h1 = h1 > 0.f ? h1 : 0.01f * h1;
    float4 wla = *(const float4*)(Wl2 + (size_t)(2 * l) * 4);
    float4 wlb = *(const float4*)(Wl2 + (size_t)(2 * l + 1) * 4);
    float4 wra = *(const float4*)(Wr2 + (size_t)(2 * l) * 4);
    float4 wrb = *(const float4*)(Wr2 + (size_t)(2 * l + 1) * 4);
    float q0 = red64(h0 * wla.x + h1 * wlb.x);
    float q1 = red64(h0 * wla.y + h1 * wlb.y);
    float q2 = red64(h0 * wla.z + h1 * wlb.z);
    float q3 = red64(h0 * wla.w + h1 * wlb.w);
    float q4 = red64(h0 * wra.x + h1 * wrb.x);
    float q5 = red64(h0 * wra.y + h1 * wrb.y);
    float q6 = red64(h0 * wra.z + h1 * wrb.z);
    float q7 = red64(h0 * wra.w + h1 * wrb.w);
    if (l == 0) {
        *(float4*)(xl2 + (size_t)n * 4) = make_float4(q0, q1, q2, q3);
        *(float4*)(xr2 + (size_t)n * 4) = make_float4(q4, q5, q6, q7);
    }
}

// layer 2 fused: 16 lanes per node (4 nodes per wave), one-pass softmax + head-mean
__global__ __launch_bounds__(256) void k_fused2(
    const int* __restrict__ src, const int* __restrict__ rowptr, const int* __restrict__ csr,
    const float* __restrict__ xl2, const float* __restrict__ xr2,
    const float* __restrict__ qe2, const float* __restrict__ qself2,
    const float* __restrict__ att2, float* __restrict__ out, int N) {
    int t = threadIdx.x;
    int l = t & 63;
    int g = l & 15;
    int node = (((blockIdx.x * 256 + t) >> 6) << 2) + (l >> 4);
    if (node >= N) return;
    int rs = rowptr[node], re = rowptr[node + 1];
    int deg = re - rs;
    float4 xrv = *(const float4*)(xr2 + (size_t)node * 4);
    float a0 = att2[0], a1 = att2[1], a2 = att2[2], a3 = att2[3];
    float ac0 = 0.f, ac1 = 0.f, ac2 = 0.f, ac3 = 0.f;
    float dn0 = 0.f, dn1 = 0.f, dn2 = 0.f, dn3 = 0.f;
    for (int slot = g; slot <= deg; slot += 16) {
        int s;
        float4 q;
        if (slot < deg) {
            int j = rs + slot;
            int eid = csr[j];
            s = src[eid];
            q = *(const float4*)(qe2 + (size_t)j * 4);
        } else {
            s = node;
            q = *(const float4*)(qself2 + (size_t)node * 4);
        }
        float4 xv = *(const float4*)(xl2 + (size_t)s * 4);
        float v0 = xv.x + xrv.x + q.x; v0 = v0 > 0.f ? v0 : 0.2f * v0;
        float v1 = xv.y + xrv.y + q.y; v1 = v1 > 0.f ? v1 : 0.2f * v1;
        float v2 = xv.z + xrv.z + q.z; v2 = v2 > 0.f ? v2 : 0.2f * v2;
        float v3 = xv.w + xrv.w + q.w; v3 = v3 > 0.f ? v3 : 0.2f * v3;
        float w0 = __expf(v0 * a0); ac0 += w0 * xv.x; dn0 += w0;
        float w1 = __expf(v1 * a1); ac1 += w1 * xv.y; dn1 += w1;
        float w2 = __expf(v2 * a2); ac2 += w2 * xv.z; dn2 += w2;
        float w3 = __expf(v3 * a3); ac3 += w3 * xv.w; dn3 += w3;
    }
    ac0 = row_sum16(ac0); ac1 = row_sum16(ac1);
    ac2 = row_sum16(ac2); ac3 = row_sum16(ac3);
    dn0 = row_sum16(dn0); dn1 = row_sum16(dn1);
    dn2 = row_sum16(dn2); dn3 = row_sum16(dn3);
    if (g == 0) {
        float r = ac0 / (dn0 + 1e-16f) + ac1 / (dn1 + 1e-16f)
                + ac2 / (dn2 + 1e-16f) + ac3 / (dn3 + 1e-16f);
        out[node] = r * 0.25f;
    }
}

extern "C" void kernel_launch(void* const* d_in, const int* in_sizes, int n_in,
                              void* d_out, int out_size, void* d_ws, size_t ws_size,
                              hipStream_t stream) {
    const float* x         = (const float*)d_in[0];
    const int*   edge_index= (const int*)d_in[1];
    const float* edge_attr = (const float*)d_in[2];
    const float* Wl1       = (const float*)d_in[3];
    const float* Wr1       = (const float*)d_in[4];
    const float* We1       = (const float*)d_in[5];
    const float* att1      = (const float*)d_in[6];
    const float* Wl2       = (const float*)d_in[7];
    const float* Wr2       = (const float*)d_in[8];
    const float* We2       = (const float*)d_in[9];
    const float* att2      = (const float*)d_in[10];
    float* outp = (float*)d_out;

    const int F = 128, HC = 128, EDIM = 16;
    int N = in_sizes[0] / F;
    int E = in_sizes[1] / 2;
    const int* src = edge_index;
    const int* dst = edge_index + E;

    char* ws = (char*)d_ws;
    size_t off = 0;
    auto alloc = [&](size_t bytes) {
        char* p = ws + off;
        off += (bytes + 255) & ~(size_t)255;
        return p;
    };
    int*    deg      = (int*)alloc((size_t)N * 4);
    int*    rowptr   = (int*)alloc((size_t)(N + 1) * 4);
    int*    cursor   = (int*)alloc((size_t)N * 4);
    int*    csr      = (int*)alloc((size_t)E * 4);
    float*  ea_perm  = (float*)alloc((size_t)E * EDIM * 4);
    float*  qe2      = (float*)alloc((size_t)E * 4 * 4);
    float*  loop_attr= (float*)alloc((size_t)N * EDIM * 4);
    float*  qself2   = (float*)alloc((size_t)N * 4 * 4);
    ushort* xl_bf    = (ushort*)alloc((size_t)N * HC * 2);
    float*  xr1      = (float*)alloc((size_t)N * HC * 4);
    float*  xl2      = (float*)alloc((size_t)N * 4 * 4);
    float*  xr2      = (float*)alloc((size_t)N * 4 * 4);

    hipMemsetAsync(deg, 0, (size_t)N * 4, stream);
    hipMemsetAsync(cursor, 0, (size_t)N * 4, stream);

    int eb = (E + 255) / 256;
    k_count_deg<<<eb, 256, 0, stream>>>(dst, deg, E);
    k_scan<<<1, 1024, 0, stream>>>(deg, rowptr, N);
    k_scatter<<<eb, 256, 0, stream>>>(dst, rowptr, cursor, csr, E);
    k_gemm1<<<(N + 31) / 32, 256, 0, stream>>>(x, Wl1, Wr1, xl_bf, xr1, N);
    k_permute<<<eb, 256, 0, stream>>>(csr, edge_attr, We2, ea_perm, qe2, E);
    k_loopq<<<(N * 20 + 255) / 256, 256, 0, stream>>>(ea_perm, qe2, rowptr, loop_attr, qself2, N);
    k_fused1<<<(N + 3) / 4, 256, 0, stream>>>(src, rowptr, csr, xl_bf, xr1, ea_perm, loop_attr,
                                              We1, att1, Wl2, Wr2, xl2, xr2, N);
    k_fused2<<<(N + 15) / 16, 256, 0, stream>>>(src, rowptr, csr, xl2, xr2, qe2, qself2,
                                                att2, outp, N);
}

// Round 4
// 456.684 us; speedup vs baseline: 1.9044x; 1.2055x over previous
//
#include <hip/hip_runtime.h>
#include <math.h>

// ---------------------------------------------------------------------------
// GATv2 x2 on MI355X. Fused one-pass-softmax structure, unroll-4 ILP:
//   memset -> count_deg -> scan1/2/3 (rowptr) -> scatter(CSR)
//   -> gemm1(xl bf16, xr f32) -> permute(ea->CSR f32 + qe2) -> loopq(self rows)
//   -> fused1(logits+softmax+aggregate+lrelu+gemv2 -> xl2,xr2)  [unroll-4 + DPP]
//   -> fused2(logits2+softmax+aggregate+head-mean -> out)       [DPP]
// Buffers ea_all/qe_all hold edge rows [0,E) in CSR order and self rows [E,E+N).
// ---------------------------------------------------------------------------

static __device__ __forceinline__ ushort f2bf(float f) {
    unsigned u = __float_as_uint(f);
    unsigned r = (u + 0x7fffu + ((u >> 16) & 1u)) >> 16;  // RNE
    return (ushort)r;
}

// sum across each 16-lane row via DPP row_ror (pure VALU, no DS)
static __device__ __forceinline__ float row_sum16(float x) {
    x += __int_as_float(__builtin_amdgcn_update_dpp(0, __float_as_int(x), 0x121, 0xf, 0xf, true));
    x += __int_as_float(__builtin_amdgcn_update_dpp(0, __float_as_int(x), 0x122, 0xf, 0xf, true));
    x += __int_as_float(__builtin_amdgcn_update_dpp(0, __float_as_int(x), 0x124, 0xf, 0xf, true));
    x += __int_as_float(__builtin_amdgcn_update_dpp(0, __float_as_int(x), 0x128, 0xf, 0xf, true));
    return x;
}

static __device__ __forceinline__ float red64(float x) {  // 64-lane sum
    x = row_sum16(x);
    x += __shfl_xor(x, 16);
    x += __shfl_xor(x, 32);
    return x;
}

__global__ void k_count_deg(const int* __restrict__ dst, int* __restrict__ deg, int E) {
    int i = blockIdx.x * blockDim.x + threadIdx.x;
    if (i < E) atomicAdd(&deg[dst[i]], 1);
}

// pass 1: per-1024-block exclusive scan + block total
__global__ __launch_bounds__(1024) void k_scan1(const int* __restrict__ deg,
                                                int* __restrict__ rowptr,
                                                int* __restrict__ part, int N) {
    __shared__ int wsum[16];
    int t = threadIdx.x, l = t & 63, w = t >> 6;
    int i = blockIdx.x * 1024 + t;
    int v = (i < N) ? deg[i] : 0;
    int sc = v;
    #pragma unroll
    for (int off = 1; off < 64; off <<= 1) {
        int y = __shfl_up(sc, off);
        if (l >= off) sc += y;
    }
    if (l == 63) wsum[w] = sc;
    __syncthreads();
    if (w == 0) {
        int pv = (l < 16) ? wsum[l] : 0;
        int psc = pv;
        #pragma unroll
        for (int off = 1; off < 16; off <<= 1) {
            int y = __shfl_up(psc, off);
            if (l >= off) psc += y;
        }
        if (l < 16) wsum[l] = psc - pv;
    }
    __syncthreads();
    if (i < N) rowptr[i] = wsum[w] + sc - v;
    if (t == 1023) part[blockIdx.x] = wsum[15] + sc;
}

// pass 2: one wave, exclusive scan of block totals (chunked by 64)
__global__ void k_scan2(int* __restrict__ part, int nb) {
    int l = threadIdx.x & 63;
    int run = 0;
    for (int base = 0; base < nb; base += 64) {
        int i = base + l;
        int v = (i < nb) ? part[i] : 0;
        int sc = v;
        #pragma unroll
        for (int off = 1; off < 64; off <<= 1) {
            int y = __shfl_up(sc, off);
            if (l >= off) sc += y;
        }
        if (i < nb) part[i] = run + sc - v;
        run += __shfl(sc, 63);
    }
}

// pass 3: add block offsets; rowptr[N] = E
__global__ void k_scan3(int* __restrict__ rowptr, const int* __restrict__ part, int N, int E) {
    int i = blockIdx.x * 256 + threadIdx.x;
    if (i < N) rowptr[i] += part[i >> 10];
    if (i == 0) rowptr[N] = E;
}

__global__ void k_scatter(const int* __restrict__ dst, const int* __restrict__ rowptr,
                          int* __restrict__ cursor, int* __restrict__ csr, int E) {
    int i = blockIdx.x * blockDim.x + threadIdx.x;
    if (i < E) {
        int d = dst[i];
        int pos = rowptr[d] + atomicAdd(&cursor[d], 1);
        csr[pos] = i;
    }
}

// xl1 = x @ Wl1 (bf16 out), xr1 = x @ Wr1 (f32 out)
__global__ __launch_bounds__(256) void k_gemm1(const float* __restrict__ x,
                                               const float* __restrict__ Wl,
                                               const float* __restrict__ Wr,
                                               ushort* __restrict__ xl, float* __restrict__ xr,
                                               int N) {
    __shared__ float xs[32 * 128];
    int r0 = blockIdx.x * 32;
    int t = threadIdx.x;
    for (int i = t * 4; i < 32 * 128; i += 256 * 4) {
        int r = i >> 7;
        float4 v = make_float4(0.f, 0.f, 0.f, 0.f);
        if (r0 + r < N) v = *(const float4*)(&x[(size_t)(r0 + r) * 128 + (i & 127)]);
        *(float4*)(&xs[i]) = v;
    }
    __syncthreads();
    int c = t & 127;
    int rbase = (t >> 7) * 16;  // 0 or 16
    float accl[16], accr[16];
    #pragma unroll
    for (int r = 0; r < 16; ++r) { accl[r] = 0.f; accr[r] = 0.f; }
    for (int k = 0; k < 128; ++k) {
        float wl = Wl[k * 128 + c];
        float wr = Wr[k * 128 + c];
        #pragma unroll
        for (int r = 0; r < 16; ++r) {
            float xv = xs[(rbase + r) * 128 + k];
            accl[r] += xv * wl;
            accr[r] += xv * wr;
        }
    }
    #pragma unroll
    for (int r = 0; r < 16; ++r) {
        int row = r0 + rbase + r;
        if (row < N) {
            xl[(size_t)row * 128 + c] = f2bf(accl[r]);
            xr[(size_t)row * 128 + c] = accr[r];
        }
    }
}

// permute edge_attr into CSR order (rows [0,E) of ea_all) and qe2 = ea@We2 -> qe_all
__global__ __launch_bounds__(256) void k_permute(const int* __restrict__ csr,
                                                 const float* __restrict__ ea,
                                                 const float* __restrict__ We2,
                                                 float* __restrict__ ea_all,
                                                 float* __restrict__ qe_all, int E) {
    __shared__ float sW[64];
    int t = threadIdx.x;
    if (t < 64) sW[t] = We2[t];
    __syncthreads();
    int j = blockIdx.x * 256 + t;
    if (j >= E) return;
    int e = csr[j];
    const float4* s4 = (const float4*)(ea + (size_t)e * 16);
    float4* d4 = (float4*)(ea_all + (size_t)j * 16);
    float q0 = 0.f, q1 = 0.f, q2 = 0.f, q3 = 0.f;
    #pragma unroll
    for (int b = 0; b < 4; ++b) {
        float4 v = s4[b];
        d4[b] = v;
        int k = 4 * b;
        q0 += v.x * sW[k * 4 + 0] + v.y * sW[(k + 1) * 4 + 0] + v.z * sW[(k + 2) * 4 + 0] + v.w * sW[(k + 3) * 4 + 0];
        q1 += v.x * sW[k * 4 + 1] + v.y * sW[(k + 1) * 4 + 1] + v.z * sW[(k + 2) * 4 + 1] + v.w * sW[(k + 3) * 4 + 1];
        q2 += v.x * sW[k * 4 + 2] + v.y * sW[(k + 1) * 4 + 2] + v.z * sW[(k + 2) * 4 + 2] + v.w * sW[(k + 3) * 4 + 2];
        q3 += v.x * sW[k * 4 + 3] + v.y * sW[(k + 1) * 4 + 3] + v.z * sW[(k + 2) * 4 + 3] + v.w * sW[(k + 3) * 4 + 3];
    }
    *(float4*)(qe_all + (size_t)j * 4) = make_float4(q0, q1, q2, q3);
}

// self rows: ea_all[E+n] = mean incoming ea; qe_all[E+n] = mean incoming qe2
__global__ __launch_bounds__(256) void k_loopq(float* __restrict__ ea_all,
                                               float* __restrict__ qe_all,
                                               const int* __restrict__ rowptr,
                                               int E, int N) {
    int idx = blockIdx.x * 256 + threadIdx.x;
    int tot1 = N * 16;
    if (idx < tot1) {
        int n = idx >> 4, k = idx & 15;
        int rs = rowptr[n], re = rowptr[n + 1];
        float s = 0.f;
        for (int j = rs; j < re; ++j) s += ea_all[(size_t)j * 16 + k];
        int dg = re - rs;
        ea_all[(size_t)(E + n) * 16 + k] = s / (float)(dg > 1 ? dg : 1);
    } else if (idx < tot1 + N * 4) {
        int i2 = idx - tot1;
        int n = i2 >> 2, c = i2 & 3;
        int rs = rowptr[n], re = rowptr[n + 1];
        float s = 0.f;
        for (int j = rs; j < re; ++j) s += qe_all[(size_t)j * 4 + c];
        int dg = re - rs;
        qe_all[(size_t)(E + n) * 4 + c] = s / (float)(dg > 1 ? dg : 1);
    }
}

// layer 1 fused (wave per node, lane l owns channels 2l,2l+1), unroll-4 chains
__global__ __launch_bounds__(256) void k_fused1(
    const int* __restrict__ src, const int* __restrict__ rowptr, const int* __restrict__ csr,
    const ushort* __restrict__ xl_bf, const float* __restrict__ xr,
    const float* __restrict__ ea_all,
    const float* __restrict__ We, const float* __restrict__ att,
    const float* __restrict__ Wl2, const float* __restrict__ Wr2,
    float* __restrict__ xl2, float* __restrict__ xr2, int E, int N) {
    int t = threadIdx.x;
    int l = t & 63;
    int n = (blockIdx.x * 256 + t) >> 6;
    if (n >= N) return;
    float2 we[16];
    #pragma unroll
    for (int k = 0; k < 16; ++k) we[k] = *(const float2*)(We + k * 128 + 2 * l);
    float2 av  = *(const float2*)(att + 2 * l);
    float2 xrv = *(const float2*)(xr + (size_t)n * 128 + 2 * l);
    int rs = rowptr[n], re = rowptr[n + 1];
    int deg = re - rs;
    int nslots = deg + 1;  // + self loop at the end
    // prefetch this node's source ids into lanes (fast path deg<=64)
    int srcv = n;
    if (l < deg) srcv = src[csr[rs + l]];
    float acc0 = 0.f, acc1 = 0.f, den = 0.f;
    for (int base = 0; base < nslots; base += 4) {
        int sA[4], rowA[4];
        float mask[4];
        #pragma unroll
        for (int c = 0; c < 4; ++c) {
            int slot = base + c;
            bool valid = slot < nslots;
            mask[c] = valid ? 1.f : 0.f;
            int eff = valid ? slot : deg;
            int s, row;
            if (eff < deg) {
                s = (eff < 64) ? __shfl(srcv, eff) : src[csr[rs + eff]];
                row = rs + eff;
            } else {
                s = n;
                row = E + n;
            }
            sA[c] = s;
            rowA[c] = row;
        }
        // issue all loads up front (16 independent chains' worth)
        unsigned xw[4];
        #pragma unroll
        for (int c = 0; c < 4; ++c)
            xw[c] = *(const unsigned*)(xl_bf + (size_t)sA[c] * 128 + 2 * l);
        float4 ea[4][4];
        #pragma unroll
        for (int c = 0; c < 4; ++c) {
            const float4* p = (const float4*)(ea_all + (size_t)rowA[c] * 16);
            ea[c][0] = p[0]; ea[c][1] = p[1]; ea[c][2] = p[2]; ea[c][3] = p[3];
        }
        #pragma unroll
        for (int c = 0; c < 4; ++c) {
            const float* a = (const float*)&ea[c][0];
            float vx = xrv.x, vy = xrv.y;
            #pragma unroll
            for (int k = 0; k < 16; ++k) { vx += a[k] * we[k].x; vy += a[k] * we[k].y; }
            float xl0 = __uint_as_float(xw[c] << 16);
            float xl1 = __uint_as_float(xw[c] & 0xffff0000u);
            vx += xl0; vy += xl1;
            vx = vx > 0.f ? vx : 0.2f * vx;
            vy = vy > 0.f ? vy : 0.2f * vy;
            float p = row_sum16(av.x * vx + av.y * vy);
            float w = __expf(p) * mask[c];
            acc0 += w * xl0;
            acc1 += w * xl1;
            den  += w;
        }
    }
    float rdn = 1.f / (den + 1e-16f);
    float h0 = acc0 * rdn, h1 = acc1 * rdn;
    h0 = h0 > 0.f ? h0 : 0.01f * h0;
    h1 = h1 > 0.f ? h1 : 0.01f * h1;
    float4 wla = *(const float4*)(Wl2 + (size_t)(2 * l) * 4);
    float4 wlb = *(const float4*)(Wl2 + (size_t)(2 * l + 1) * 4);
    float4 wra = *(const float4*)(Wr2 + (size_t)(2 * l) * 4);
    float4 wrb = *(const float4*)(Wr2 + (size_t)(2 * l + 1) * 4);
    float q0 = red64(h0 * wla.x + h1 * wlb.x);
    float q1 = red64(h0 * wla.y + h1 * wlb.y);
    float q2 = red64(h0 * wla.z + h1 * wlb.z);
    float q3 = red64(h0 * wla.w + h1 * wlb.w);
    float q4 = red64(h0 * wra.x + h1 * wrb.x);
    float q5 = red64(h0 * wra.y + h1 * wrb.y);
    float q6 = red64(h0 * wra.z + h1 * wrb.z);
    float q7 = red64(h0 * wra.w + h1 * wrb.w);
    if (l == 0) {
        *(float4*)(xl2 + (size_t)n * 4) = make_float4(q0, q1, q2, q3);
        *(float4*)(xr2 + (size_t)n * 4) = make_float4(q4, q5, q6, q7);
    }
}

// layer 2 fused: 16 lanes per node (4 nodes per wave), one-pass softmax + head-mean
__global__ __launch_bounds__(256) void k_fused2(
    const int* __restrict__ src, const int* __restrict__ rowptr, const int* __restrict__ csr,
    const float* __restrict__ xl2, const float* __restrict__ xr2,
    const float* __restrict__ qe_all,
    const float* __restrict__ att2, float* __restrict__ out, int E, int N) {
    int t = threadIdx.x;
    int l = t & 63;
    int g = l & 15;
    int node = (((blockIdx.x * 256 + t) >> 6) << 2) + (l >> 4);
    if (node >= N) return;
    int rs = rowptr[node], re = rowptr[node + 1];
    int deg = re - rs;
    float4 xrv = *(const float4*)(xr2 + (size_t)node * 4);
    float a0 = att2[0], a1 = att2[1], a2 = att2[2], a3 = att2[3];
    float ac0 = 0.f, ac1 = 0.f, ac2 = 0.f, ac3 = 0.f;
    float dn0 = 0.f, dn1 = 0.f, dn2 = 0.f, dn3 = 0.f;
    for (int slot = g; slot <= deg; slot += 16) {
        int s, row;
        if (slot < deg) {
            row = rs + slot;
            s = src[csr[row]];
        } else {
            row = E + node;
            s = node;
        }
        float4 q = *(const float4*)(qe_all + (size_t)row * 4);
        float4 xv = *(const float4*)(xl2 + (size_t)s * 4);
        float v0 = xv.x + xrv.x + q.x; v0 = v0 > 0.f ? v0 : 0.2f * v0;
        float v1 = xv.y + xrv.y + q.y; v1 = v1 > 0.f ? v1 : 0.2f * v1;
        float v2 = xv.z + xrv.z + q.z; v2 = v2 > 0.f ? v2 : 0.2f * v2;
        float v3 = xv.w + xrv.w + q.w; v3 = v3 > 0.f ? v3 : 0.2f * v3;
        float w0 = __expf(v0 * a0); ac0 += w0 * xv.x; dn0 += w0;
        float w1 = __expf(v1 * a1); ac1 += w1 * xv.y; dn1 += w1;
        float w2 = __expf(v2 * a2); ac2 += w2 * xv.z; dn2 += w2;
        float w3 = __expf(v3 * a3); ac3 += w3 * xv.w; dn3 += w3;
    }
    ac0 = row_sum16(ac0); ac1 = row_sum16(ac1);
    ac2 = row_sum16(ac2); ac3 = row_sum16(ac3);
    dn0 = row_sum16(dn0); dn1 = row_sum16(dn1);
    dn2 = row_sum16(dn2); dn3 = row_sum16(dn3);
    if (g == 0) {
        float r = ac0 / (dn0 + 1e-16f) + ac1 / (dn1 + 1e-16f)
                + ac2 / (dn2 + 1e-16f) + ac3 / (dn3 + 1e-16f);
        out[node] = r * 0.25f;
    }
}

extern "C" void kernel_launch(void* const* d_in, const int* in_sizes, int n_in,
                              void* d_out, int out_size, void* d_ws, size_t ws_size,
                              hipStream_t stream) {
    const float* x         = (const float*)d_in[0];
    const int*   edge_index= (const int*)d_in[1];
    const float* edge_attr = (const float*)d_in[2];
    const float* Wl1       = (const float*)d_in[3];
    const float* Wr1       = (const float*)d_in[4];
    const float* We1       = (const float*)d_in[5];
    const float* att1      = (const float*)d_in[6];
    const float* Wl2       = (const float*)d_in[7];
    const float* Wr2       = (const float*)d_in[8];
    const float* We2       = (const float*)d_in[9];
    const float* att2      = (const float*)d_in[10];
    float* outp = (float*)d_out;

    const int F = 128, HC = 128, EDIM = 16;
    int N = in_sizes[0] / F;
    int E = in_sizes[1] / 2;
    const int* src = edge_index;
    const int* dst = edge_index + E;

    char* ws = (char*)d_ws;
    size_t off = 0;
    auto alloc = [&](size_t bytes) {
        char* p = ws + off;
        off += (bytes + 255) & ~(size_t)255;
        return p;
    };
    int*    deg      = (int*)alloc((size_t)N * 4);
    int*    cursor   = (int*)alloc((size_t)N * 4);
    int*    rowptr   = (int*)alloc((size_t)(N + 1) * 4);
    int*    part     = (int*)alloc(((size_t)N / 1024 + 2) * 4);
    int*    csr      = (int*)alloc((size_t)E * 4);
    float*  ea_all   = (float*)alloc((size_t)(E + N) * EDIM * 4);
    float*  qe_all   = (float*)alloc((size_t)(E + N) * 4 * 4);
    ushort* xl_bf    = (ushort*)alloc((size_t)N * HC * 2);
    float*  xr1      = (float*)alloc((size_t)N * HC * 4);
    float*  xl2      = (float*)alloc((size_t)N * 4 * 4);
    float*  xr2      = (float*)alloc((size_t)N * 4 * 4);

    // deg and cursor are adjacent: one memset covers both
    hipMemsetAsync(deg, 0, (size_t)((char*)rowptr - (char*)deg), stream);

    int eb = (E + 255) / 256;
    int nb = (N + 1023) / 1024;
    k_count_deg<<<eb, 256, 0, stream>>>(dst, deg, E);
    k_scan1<<<nb, 1024, 0, stream>>>(deg, rowptr, part, N);
    k_scan2<<<1, 64, 0, stream>>>(part, nb);
    k_scan3<<<(N + 255) / 256, 256, 0, stream>>>(rowptr, part, N, E);
    k_scatter<<<eb, 256, 0, stream>>>(dst, rowptr, cursor, csr, E);
    k_gemm1<<<(N + 31) / 32, 256, 0, stream>>>(x, Wl1, Wr1, xl_bf, xr1, N);
    k_permute<<<eb, 256, 0, stream>>>(csr, edge_attr, We2, ea_all, qe_all, E);
    k_loopq<<<(N * 20 + 255) / 256, 256, 0, stream>>>(ea_all, qe_all, rowptr, E, N);
    k_fused1<<<(N + 3) / 4, 256, 0, stream>>>(src, rowptr, csr, xl_bf, xr1, ea_all,
                                              We1, att1, Wl2, Wr2, xl2, xr2, E, N);
    k_fused2<<<(N + 15) / 16, 256, 0, stream>>>(src, rowptr, csr, xl2, xr2, qe_all,
                                                att2, outp, E, N);
}